// Round 1
// baseline (126.768 us; speedup 1.0000x reference)
//
#include <hip/hip_runtime.h>
#include <math.h>

#define NB 1024
#define NR 512
#define ND 256

constexpr float kBETA  = 6.0f;
constexpr float kLOG2E = 1.4426950408889634f;

#if __has_builtin(__builtin_amdgcn_exp2f)
__device__ __forceinline__ float fast_exp2(float x) { return __builtin_amdgcn_exp2f(x); }
#else
__device__ __forceinline__ float fast_exp2(float x) { return exp2f(x); }
#endif
#if __has_builtin(__builtin_amdgcn_rcpf)
__device__ __forceinline__ float fast_rcp(float x) { return __builtin_amdgcn_rcpf(x); }
#else
__device__ __forceinline__ float fast_rcp(float x) { return 1.0f / x; }
#endif

// Prep: fold all (R,D)-only math into P4[r*ND+d] = {s*t_low, s*t_high, m*tanh(e_low),
// m*tanh(e_high)} with s = kappa*log2(e); baseR[r] = sum_d (mel+meh); y init = head_b.
__global__ __launch_bounds__(256) void prep_kernel(
    const float* __restrict__ center, const float* __restrict__ log_width,
    const float* __restrict__ e_low, const float* __restrict__ e_high,
    const float* __restrict__ mask, const float* __restrict__ log_kappa,
    const float* __restrict__ head_b,
    float4* __restrict__ P4, float* __restrict__ baseR, float* __restrict__ y)
{
    const int t = threadIdx.x;
    const int r = blockIdx.x * 4 + (t >> 6);   // 128 blocks * 4 waves = 512 r
    const int lane = t & 63;

    const float kappa = fminf(fmaxf(fast_exp2(log_kappa[0] * kLOG2E), 0.5f), 50.0f);
    const float s = kappa * kLOG2E;

    float mpmsum = 0.0f;
    #pragma unroll
    for (int j = 0; j < 4; ++j) {
        const int d = lane + 64 * j;
        const int idx = r * ND + d;
        const float w  = fminf(fmaxf(fast_exp2(log_width[idx] * kLOG2E), 0.001f), 50.0f);
        const float c  = center[idx];
        const float m  = fast_rcp(1.0f + fast_exp2(-mask[idx] * kLOG2E));
        const float mel = m * tanhf(e_low[idx]);
        const float meh = m * tanhf(e_high[idx]);
        float4 p;
        p.x = s * (c - 0.5f * w);
        p.y = s * (c + 0.5f * w);
        p.z = mel;
        p.w = meh;
        P4[idx] = p;
        mpmsum += mel + meh;
    }
    #pragma unroll
    for (int off = 32; off > 0; off >>= 1) mpmsum += __shfl_down(mpmsum, off, 64);
    if (lane == 0) baseR[r] = mpmsum;

    const int gid = blockIdx.x * 256 + t;      // first 4 blocks cover 1024 outputs
    if (gid < NB) y[gid] = head_b[0];
}

// Main: block = 512 threads (8 waves). blockIdx.x -> 64-b tile (lane = b),
// blockIdx.y*8 + wave -> r. Per-lane d-loop does the whole D-reduction in-register.
__global__ __launch_bounds__(512) void evid_kernel(
    const float* __restrict__ x, const float* __restrict__ log_kappa,
    const float* __restrict__ t_arr, const float* __restrict__ head_w,
    const float4* __restrict__ P4, const float* __restrict__ baseR,
    float* __restrict__ y)
{
    __shared__ float xs[64 * 257];   // 64 b-rows, stride 257 -> conflict-free reads

    const int tid = threadIdx.x;
    const int b0 = blockIdx.x * 64;

    const float kappa = fminf(fmaxf(fast_exp2(log_kappa[0] * kLOG2E), 0.5f), 50.0f);
    const float s = kappa * kLOG2E;

    // Stage x tile (64x256 f32), pre-scaled by s. Coalesced float4 global reads.
    const float4* xg = (const float4*)(x + (size_t)b0 * ND);
    #pragma unroll
    for (int k = 0; k < 8; ++k) {
        const int i = tid + k * 512;         // 4096 float4s
        const float4 v = xg[i];
        const int bb = i >> 6;
        const int cc = (i & 63) << 2;
        float* p = &xs[bb * 257 + cc];
        p[0] = s * v.x; p[1] = s * v.y; p[2] = s * v.z; p[3] = s * v.w;
    }
    __syncthreads();

    const int lane = tid & 63;
    const int r = __builtin_amdgcn_readfirstlane(blockIdx.y * 8 + (tid >> 6));

    const float4* __restrict__ pr = P4 + r * ND;   // wave-uniform -> s_load
    const float* xrow = &xs[lane * 257];

    float acc0 = 0.0f, acc1 = 0.0f;
    #pragma unroll 8
    for (int d = 0; d < ND; d += 2) {
        {
            const float4 p = pr[d];
            const float X = xrow[d];
            const float E1 = fast_exp2(p.x - X);
            const float E2 = fast_exp2(X - p.y);
            const float E1p = E1 + 1.0f;
            const float E2p = E2 + 1.0f;
            const float num = fmaf(p.z, E2p, p.w * E1p);
            acc0 = fmaf(num, fast_rcp(E1p * E2p), acc0);
        }
        {
            const float4 p = pr[d + 1];
            const float X = xrow[d + 1];
            const float E1 = fast_exp2(p.x - X);
            const float E2 = fast_exp2(X - p.y);
            const float E1p = E1 + 1.0f;
            const float E2p = E2 + 1.0f;
            const float num = fmaf(p.z, E2p, p.w * E1p);
            acc1 = fmaf(num, fast_rcp(E1p * E2p), acc1);
        }
    }

    const float ev = baseR[r] - 2.0f * (acc0 + acc1);
    const float u = (kBETA * kLOG2E) * (t_arr[r] - ev);     // sigmoid via exp2
    const float z = fast_rcp(1.0f + fast_exp2(u));
    atomicAdd(&y[b0 + lane], z * head_w[r]);
}

extern "C" void kernel_launch(void* const* d_in, const int* in_sizes, int n_in,
                              void* d_out, int out_size, void* d_ws, size_t ws_size,
                              hipStream_t stream) {
    const float* x         = (const float*)d_in[0];
    const float* center    = (const float*)d_in[1];
    const float* log_width = (const float*)d_in[2];
    const float* e_low     = (const float*)d_in[3];
    const float* e_high    = (const float*)d_in[4];
    const float* mask      = (const float*)d_in[5];
    const float* log_kappa = (const float*)d_in[6];
    const float* t_arr     = (const float*)d_in[7];
    const float* head_w    = (const float*)d_in[8];
    const float* head_b    = (const float*)d_in[9];
    float* y = (float*)d_out;

    float4* P4   = (float4*)d_ws;                                  // 2 MB
    float* baseR = (float*)((char*)d_ws + sizeof(float4) * NR * ND); // +2 KB

    prep_kernel<<<NR / 4, 256, 0, stream>>>(center, log_width, e_low, e_high,
                                            mask, log_kappa, head_b, P4, baseR, y);
    evid_kernel<<<dim3(NB / 64, NR / 8), 512, 0, stream>>>(x, log_kappa, t_arr,
                                                           head_w, P4, baseR, y);
}

// Round 2
// 121.279 us; speedup vs baseline: 1.0453x; 1.0453x over previous
//
#include <hip/hip_runtime.h>
#include <math.h>

#define NB 1024
#define NR 512
#define ND 256
#define XS_STRIDE 258   // odd*2: b64 LDS reads land 4 dwords/bank (floor), 8B-aligned

typedef float v2f __attribute__((ext_vector_type(2)));

constexpr float kBETA  = 6.0f;
constexpr float kLOG2E = 1.4426950408889634f;

#if __has_builtin(__builtin_amdgcn_exp2f)
__device__ __forceinline__ float fast_exp2(float x) { return __builtin_amdgcn_exp2f(x); }
#else
__device__ __forceinline__ float fast_exp2(float x) { return exp2f(x); }
#endif
#if __has_builtin(__builtin_amdgcn_rcpf)
__device__ __forceinline__ float fast_rcp(float x) { return __builtin_amdgcn_rcpf(x); }
#else
__device__ __forceinline__ float fast_rcp(float x) { return 1.0f / x; }
#endif

__device__ __forceinline__ float fast_sigmoid(float a) {   // 1/(1+e^-a)
    return fast_rcp(1.0f + fast_exp2(-a * kLOG2E));
}
__device__ __forceinline__ float fast_tanh(float a) {      // 1 - 2/(1+e^{2a})
    return 1.0f - 2.0f * fast_rcp(1.0f + fast_exp2(a * (2.0f * kLOG2E)));
}

// Pre-pair constants for VOP3P: P8[r][j] = {ssy.xy, K.xy, mel.xy, meh.xy} (32B per d-pair)
//   ssy = s*t_high, K = exp2(-s*width) (E1 = K/t), mel = sig(mask)*tanh(e_low), meh likewise.
// One thread per (r,d). 512 blocks x 256 threads -> 2048 waves.
__global__ __launch_bounds__(256) void prep_kernel(
    const float* __restrict__ center, const float* __restrict__ log_width,
    const float* __restrict__ e_low, const float* __restrict__ e_high,
    const float* __restrict__ mask, const float* __restrict__ log_kappa,
    const float* __restrict__ head_b,
    float* __restrict__ P8, float* __restrict__ baseR, float* __restrict__ y)
{
    const int r = blockIdx.x;
    const int d = threadIdx.x;
    const int idx = r * ND + d;

    const float kappa = fminf(fmaxf(fast_exp2(log_kappa[0] * kLOG2E), 0.5f), 50.0f);
    const float s = kappa * kLOG2E;

    const float wdt = fminf(fmaxf(fast_exp2(log_width[idx] * kLOG2E), 0.001f), 50.0f);
    const float th  = center[idx] + 0.5f * wdt;
    const float ssy = s * th;
    const float K   = fmaxf(fast_exp2(-s * wdt), 1e-30f);   // floor: keeps den > 0
    const float m   = fast_sigmoid(mask[idx]);
    const float mel = m * fast_tanh(e_low[idx]);
    const float meh = m * fast_tanh(e_high[idx]);

    float* P = P8 + (size_t)r * 1024 + (d >> 1) * 8 + (d & 1);
    P[0] = ssy; P[2] = K; P[4] = mel; P[6] = meh;

    // baseR[r] = sum_d (mel+meh)
    float v = mel + meh;
    #pragma unroll
    for (int off = 32; off > 0; off >>= 1) v += __shfl_down(v, off, 64);
    __shared__ float red[4];
    if ((d & 63) == 0) red[d >> 6] = v;
    __syncthreads();
    if (d == 0) baseR[r] = red[0] + red[1] + red[2] + red[3];

    const int gid = blockIdx.x * 256 + threadIdx.x;
    if (gid < NB) y[gid] = head_b[0];
}

// Main: 1024 threads = 16 waves; wave w -> r = blockIdx.y*16 + w; lane = b.
// Inner loop per d-pair: 2 exp + 2 rcp (trans) + ~8 packed-fp32 ops.
//   acc_elem = mel*t/(t+K) + meh/(t+1) = (mel*t*u + meh*v) / (u*v),  u=t+1, v=t+K
//   evidence = baseR - 2*sum(acc_elem)
__global__ __launch_bounds__(1024, 8) void evid_kernel(
    const float* __restrict__ x, const float* __restrict__ log_kappa,
    const float* __restrict__ t_arr, const float* __restrict__ head_w,
    const float* __restrict__ P8, const float* __restrict__ baseR,
    float* __restrict__ y)
{
    __shared__ float xs[64 * XS_STRIDE];

    const int tid = threadIdx.x;
    const int b0 = blockIdx.x * 64;

    const float kappa = fminf(fmaxf(fast_exp2(log_kappa[0] * kLOG2E), 0.5f), 50.0f);
    const float s = kappa * kLOG2E;

    // Stage 64x256 x-tile pre-scaled by s; float2 LDS writes (8B aligned, 4 dw/bank).
    const float4* xg = (const float4*)(x + (size_t)b0 * ND);
    #pragma unroll
    for (int k = 0; k < 4; ++k) {
        const int i = tid + k * 1024;       // 4096 float4s
        const float4 vv = xg[i];
        const int bb = i >> 6;
        const int cc = (i & 63) << 2;
        float* p = xs + bb * XS_STRIDE + cc;
        v2f lo = { s * vv.x, s * vv.y };
        v2f hi = { s * vv.z, s * vv.w };
        *(v2f*)p = lo;
        *(v2f*)(p + 2) = hi;
    }
    __syncthreads();

    const int lane = tid & 63;
    const int w = tid >> 6;
    const int r = __builtin_amdgcn_readfirstlane(blockIdx.y * 16 + w);

    const v2f* __restrict__ pp = (const v2f*)(P8 + (size_t)r * 1024); // s_load_dwordx8/pair
    const v2f* xrow = (const v2f*)(xs + lane * XS_STRIDE);

    v2f acc = {0.0f, 0.0f};
    const v2f lim = {60.0f, 60.0f};   // arg clamp: t<=2^60 keeps t*u, u*v finite
    #pragma unroll 2
    for (int j = 0; j < 128; ++j) {
        const v2f ssy = pp[4 * j + 0];
        const v2f K   = pp[4 * j + 1];
        const v2f mel = pp[4 * j + 2];
        const v2f meh = pp[4 * j + 3];
        const v2f X = xrow[j];                       // ds_read_b64
        const v2f arg = __builtin_elementwise_min(X - ssy, lim);
        v2f t; t.x = fast_exp2(arg.x); t.y = fast_exp2(arg.y);
        const v2f u  = t + 1.0f;
        const v2f vK = t + K;
        const v2f tu = t * u;
        const v2f num = __builtin_elementwise_fma(mel, tu, meh * vK);
        const v2f den = u * vK;
        v2f rd; rd.x = fast_rcp(den.x); rd.y = fast_rcp(den.y);
        acc = __builtin_elementwise_fma(num, rd, acc);
    }

    const float ev = baseR[r] - 2.0f * (acc.x + acc.y);
    const float za = (kBETA * kLOG2E) * (t_arr[r] - ev);
    const float z = fast_rcp(1.0f + fast_exp2(za));
    const float zw = z * head_w[r];

    // Block-level reduction over the 16 waves (16 r's), then 1 atomic per lane.
    __syncthreads();
    xs[w * 64 + lane] = zw;
    __syncthreads();
    if (w == 0) {
        float ssum = 0.0f;
        #pragma unroll
        for (int q = 0; q < 16; ++q) ssum += xs[q * 64 + lane];
        atomicAdd(&y[b0 + lane], ssum);
    }
}

extern "C" void kernel_launch(void* const* d_in, const int* in_sizes, int n_in,
                              void* d_out, int out_size, void* d_ws, size_t ws_size,
                              hipStream_t stream) {
    const float* x         = (const float*)d_in[0];
    const float* center    = (const float*)d_in[1];
    const float* log_width = (const float*)d_in[2];
    const float* e_low     = (const float*)d_in[3];
    const float* e_high    = (const float*)d_in[4];
    const float* mask      = (const float*)d_in[5];
    const float* log_kappa = (const float*)d_in[6];
    const float* t_arr     = (const float*)d_in[7];
    const float* head_w    = (const float*)d_in[8];
    const float* head_b    = (const float*)d_in[9];
    float* y = (float*)d_out;

    float* P8    = (float*)d_ws;                                   // 2 MB
    float* baseR = (float*)((char*)d_ws + sizeof(float) * NR * 1024);

    prep_kernel<<<NR, 256, 0, stream>>>(center, log_width, e_low, e_high,
                                        mask, log_kappa, head_b, P8, baseR, y);
    evid_kernel<<<dim3(NB / 64, NR / 16), 1024, 0, stream>>>(x, log_kappa, t_arr,
                                                             head_w, P8, baseR, y);
}

// Round 3
// 107.953 us; speedup vs baseline: 1.1743x; 1.1234x over previous
//
#include <hip/hip_runtime.h>
#include <math.h>

#define NB 1024
#define NR 512
#define ND 256
#define XS_STRIDE 258   // even (8B-aligned v2f), 2-way bank alias on b64 reads = free

typedef float v2f __attribute__((ext_vector_type(2)));

constexpr float kBETA  = 6.0f;
constexpr float kLOG2E = 1.4426950408889634f;

#if __has_builtin(__builtin_amdgcn_exp2f)
__device__ __forceinline__ float fast_exp2(float x) { return __builtin_amdgcn_exp2f(x); }
#else
__device__ __forceinline__ float fast_exp2(float x) { return exp2f(x); }
#endif
#if __has_builtin(__builtin_amdgcn_rcpf)
__device__ __forceinline__ float fast_rcp(float x) { return __builtin_amdgcn_rcpf(x); }
#else
__device__ __forceinline__ float fast_rcp(float x) { return 1.0f / x; }
#endif

__device__ __forceinline__ float fast_sigmoid(float a) {   // 1/(1+e^-a)
    return fast_rcp(1.0f + fast_exp2(-a * kLOG2E));
}
__device__ __forceinline__ float fast_tanh(float a) {      // 1 - 2/(1+e^{2a})
    return 1.0f - 2.0f * fast_rcp(1.0f + fast_exp2(a * (2.0f * kLOG2E)));
}

// Prep: P8[r][pair j] = {E.xy, K.xy, mel.xy, meh.xy}  (32B per d-pair)
//   E = exp2(-s*t_high)  (so b = Xe*E with Xe = exp2(s*x): exp is separable!)
//   K = exp2(-s*width), mel = sig(mask)*tanh(e_low), meh likewise.
__global__ __launch_bounds__(256) void prep_kernel(
    const float* __restrict__ center, const float* __restrict__ log_width,
    const float* __restrict__ e_low, const float* __restrict__ e_high,
    const float* __restrict__ mask, const float* __restrict__ log_kappa,
    const float* __restrict__ head_b,
    float* __restrict__ P8, float* __restrict__ baseR, float* __restrict__ y)
{
    const int r = blockIdx.x;
    const int d = threadIdx.x;
    const int idx = r * ND + d;

    const float kappa = fminf(fmaxf(fast_exp2(log_kappa[0] * kLOG2E), 0.5f), 50.0f);
    const float s = kappa * kLOG2E;

    const float wdt = fminf(fmaxf(fast_exp2(log_width[idx] * kLOG2E), 0.001f), 50.0f);
    const float th  = center[idx] + 0.5f * wdt;
    const float E   = fast_exp2(-s * th);
    const float K   = fmaxf(fast_exp2(-s * wdt), 1e-30f);   // floor: keeps den > 0
    const float m   = fast_sigmoid(mask[idx]);
    const float mel = m * fast_tanh(e_low[idx]);
    const float meh = m * fast_tanh(e_high[idx]);

    float* P = P8 + (size_t)r * 1024 + (d >> 1) * 8 + (d & 1);
    P[0] = E; P[2] = K; P[4] = mel; P[6] = meh;

    // baseR[r] = sum_d (mel+meh)
    float v = mel + meh;
    #pragma unroll
    for (int off = 32; off > 0; off >>= 1) v += __shfl_down(v, off, 64);
    __shared__ float red[4];
    if ((d & 63) == 0) red[d >> 6] = v;
    __syncthreads();
    if (d == 0) baseR[r] = red[0] + red[1] + red[2] + red[3];

    const int gid = blockIdx.x * 256 + threadIdx.x;
    if (gid < NB) y[gid] = head_b[0];
}

// Per d-pair: b = Xe*E (separated exp); elem-pair contribution
//   acc += [mel*b*(b+1) + meh*(b+K)] / [(b+1)(b+K)]     (= baseR - ... identity)
// 8 packed ops + 2 rcp; NO exp in the loop.
__device__ __forceinline__ void pairstep(const v2f X, const v2f E, const v2f K,
                                         const v2f mel, const v2f meh, v2f& acc)
{
    const v2f b   = X * E;
    const v2f u   = b + 1.0f;
    const v2f vv  = b + K;
    const v2f tu  = b * u;
    const v2f mv  = meh * vv;
    const v2f num = __builtin_elementwise_fma(mel, tu, mv);
    const v2f den = u * vv;
    v2f rd; rd.x = fast_rcp(den.x); rd.y = fast_rcp(den.y);
    acc = __builtin_elementwise_fma(num, rd, acc);
}

// Main: 1024 threads = 16 waves; wave w -> r = blockIdx.y*16 + w; lane = b.
// LDS holds Xe = exp2(s*x) tile (64 x 256). Inner loop: 4-pair batches with
// register prefetch of the next batch's Xe to hide ds_read latency.
__global__ __launch_bounds__(1024, 8) void evid_kernel(
    const float* __restrict__ x, const float* __restrict__ log_kappa,
    const float* __restrict__ t_arr, const float* __restrict__ head_w,
    const float* __restrict__ P8, const float* __restrict__ baseR,
    float* __restrict__ y)
{
    __shared__ float xs[64 * XS_STRIDE + 16];   // +16 floats: prefetch overread pad

    const int tid = threadIdx.x;
    const int b0 = blockIdx.x * 64;

    const float kappa = fminf(fmaxf(fast_exp2(log_kappa[0] * kLOG2E), 0.5f), 50.0f);
    const float s = kappa * kLOG2E;

    // Stage Xe = exp2(s*x) tile; coalesced float4 global reads, v2f LDS writes.
    const float4* xg = (const float4*)(x + (size_t)b0 * ND);
    #pragma unroll
    for (int k = 0; k < 4; ++k) {
        const int i = tid + k * 1024;       // 4096 float4s
        const float4 vv = xg[i];
        const int bb = i >> 6;
        const int cc = (i & 63) << 2;
        float* p = xs + bb * XS_STRIDE + cc;
        v2f lo = { fast_exp2(s * vv.x), fast_exp2(s * vv.y) };
        v2f hi = { fast_exp2(s * vv.z), fast_exp2(s * vv.w) };
        *(v2f*)p = lo;
        *(v2f*)(p + 2) = hi;
    }
    __syncthreads();

    const int lane = tid & 63;
    const int w = tid >> 6;
    const int r = __builtin_amdgcn_readfirstlane(blockIdx.y * 16 + w);

    const v2f* __restrict__ pp = (const v2f*)(P8 + (size_t)r * 1024); // SGPR path
    const v2f* xrow = (const v2f*)(xs + lane * XS_STRIDE);

    v2f acc0 = {0.0f, 0.0f}, acc1 = {0.0f, 0.0f};
    v2f Xc0 = xrow[0], Xc1 = xrow[1], Xc2 = xrow[2], Xc3 = xrow[3];

    for (int t = 0; t < 32; ++t) {
        // prefetch next batch (t=31 reads the pad; values unused)
        const v2f Xn0 = xrow[4 * t + 4];
        const v2f Xn1 = xrow[4 * t + 5];
        const v2f Xn2 = xrow[4 * t + 6];
        const v2f Xn3 = xrow[4 * t + 7];
        const v2f* pb = pp + 16 * t;
        pairstep(Xc0, pb[0],  pb[1],  pb[2],  pb[3],  acc0);
        pairstep(Xc1, pb[4],  pb[5],  pb[6],  pb[7],  acc1);
        pairstep(Xc2, pb[8],  pb[9],  pb[10], pb[11], acc0);
        pairstep(Xc3, pb[12], pb[13], pb[14], pb[15], acc1);
        Xc0 = Xn0; Xc1 = Xn1; Xc2 = Xn2; Xc3 = Xn3;
    }

    const float ev = baseR[r] - 2.0f * (acc0.x + acc0.y + acc1.x + acc1.y);
    const float za = (kBETA * kLOG2E) * (t_arr[r] - ev);
    const float z = fast_rcp(1.0f + fast_exp2(za));
    const float zw = z * head_w[r];

    // Block-level reduction over the 16 waves (16 r's), then 1 atomic per lane.
    __syncthreads();
    xs[w * 64 + lane] = zw;
    __syncthreads();
    if (w == 0) {
        float ssum = 0.0f;
        #pragma unroll
        for (int q = 0; q < 16; ++q) ssum += xs[q * 64 + lane];
        atomicAdd(&y[b0 + lane], ssum);
    }
}

extern "C" void kernel_launch(void* const* d_in, const int* in_sizes, int n_in,
                              void* d_out, int out_size, void* d_ws, size_t ws_size,
                              hipStream_t stream) {
    const float* x         = (const float*)d_in[0];
    const float* center    = (const float*)d_in[1];
    const float* log_width = (const float*)d_in[2];
    const float* e_low     = (const float*)d_in[3];
    const float* e_high    = (const float*)d_in[4];
    const float* mask      = (const float*)d_in[5];
    const float* log_kappa = (const float*)d_in[6];
    const float* t_arr     = (const float*)d_in[7];
    const float* head_w    = (const float*)d_in[8];
    const float* head_b    = (const float*)d_in[9];
    float* y = (float*)d_out;

    float* P8    = (float*)d_ws;                                   // 2 MB
    float* baseR = (float*)((char*)d_ws + sizeof(float) * NR * 1024);

    prep_kernel<<<NR, 256, 0, stream>>>(center, log_width, e_low, e_high,
                                        mask, log_kappa, head_b, P8, baseR, y);
    evid_kernel<<<dim3(NB / 64, NR / 16), 1024, 0, stream>>>(x, log_kappa, t_arr,
                                                             head_w, P8, baseR, y);
}